// Round 20
// baseline (45.532 us; speedup 1.0000x reference)
//
#include <hip/hip_runtime.h>

#define NATOMS 13
#define NP (NATOMS * NATOMS)   // 169

constexpr int N_ = 1024;   // rows
constexpr int H_ = 512;    // inner dim
constexpr int O_ = 512;    // output dim
constexpr int RB = 4;      // rows per W stream (quad)
constexpr int OSPLIT = 2;
constexpr int OC = O_ / OSPLIT;        // 256 cols per panel
constexpr int HPH = 8;                 // h-phases = waves per block
constexpr int MAXQUAD = 384;
constexpr int NB = MAXQUAD * OSPLIT;   // 768 blocks (<= 4/CU x 256 CU capacity)
constexpr int RECS = 8;                // ints per quad record: rows[4], id, pad
constexpr unsigned TAGHI = 0x5A5Au;    // flag tag (0xAAAA poison never matches)

// ws: [0] flag = (TAGHI<<16)|nquads; records at ws+16.
// Single fused kernel. Block 0 builds the quad table DETERMINISTICALLY
// (bitmask + popcount rank: every store position is a pure function of the
// inputs -> records are bit-identical on every launch, so block 0's rewrite
// racing against readers on later launches is benign) and release-publishes;
// other blocks acquire-spin (co-resident: 4 blocks/CU x 256 >= 768).
__global__ __launch_bounds__(512, 8)
void fused_gemv(const int* __restrict__ x,
                const int* __restrict__ fact,
                const float* __restrict__ inp,
                const float* __restrict__ params,
                const float* __restrict__ bias,
                const int* __restrict__ msg_to_p,
                const int* __restrict__ order_p,
                float* __restrict__ out, int* __restrict__ ws, int N) {
    const int tid = threadIdx.x;
    const int b   = blockIdx.x;

    __shared__ float  fp_s[H_][RB];        // 8 KB
    __shared__ float4 red[HPH][RB][64];    // 32 KB — build scratch aliased here
    __shared__ int    s_nq;

    // ---------------- phase 1: block 0 builds (deterministic), others spin ---
    if (b == 0) {
        unsigned* s_mask = (unsigned*)&red[0][0][0];   // [NP][32] = 5408 ints
        int*      s_scan = (int*)(s_mask + NP * 32);   // [256]
        int*      s_sorted = s_scan + 256;             // [N_]   (total ~26.8 KB)

        for (int i = tid; i < NP * 32; i += 512) s_mask[i] = 0u;
        __syncthreads();

        // commutative bit-set: result independent of atomic order
        const int f0  = fact[2 * tid];
        const int id0 = x[f0 * 3 + 1] * NATOMS + x[f0 * 3 + 2];
        atomicOr(&s_mask[id0 * 32 + (tid >> 5)], 1u << (tid & 31));
        const int n1  = tid + 512;
        const int f1  = fact[2 * n1];
        const int id1 = x[f1 * 3 + 1] * NATOMS + x[f1 * 3 + 2];
        atomicOr(&s_mask[id1 * 32 + (n1 >> 5)], 1u << (n1 & 31));
        __syncthreads();

        // packed scan (lo16: row starts, hi16: quad starts)
        if (tid < 256) {
            int c = 0;
            if (tid < NP) {
#pragma unroll
                for (int j = 0; j < 32; ++j) c += __popc(s_mask[tid * 32 + j]);
            }
            s_scan[tid] = c | (((c + RB - 1) >> 2) << 16);
        }
        __syncthreads();
#pragma unroll
        for (int off = 1; off < 256; off <<= 1) {
            int nv = 0;
            if (tid < 256) {
                nv = s_scan[tid];
                if (tid >= off) nv += s_scan[tid - off];
            }
            __syncthreads();
            if (tid < 256) s_scan[tid] = nv;
            __syncthreads();
        }

        // deterministic scatter: rank = popcount below n within this id's mask
#define RANK_SCATTER(nn, idv) do {                                         \
        const unsigned* m = &s_mask[(idv) * 32];                           \
        const int w = (nn) >> 5, bit = (nn) & 31;                          \
        int rk = __popc(m[w] & ((bit == 0) ? 0u : ((1u << bit) - 1u)));    \
        for (int j = 0; j < w; ++j) rk += __popc(m[j]);                    \
        const int st = (idv) ? (s_scan[(idv) - 1] & 0xffff) : 0;           \
        s_sorted[st + rk] = (nn);                                          \
    } while (0)
        RANK_SCATTER(tid, id0);
        RANK_SCATTER(n1, id1);
#undef RANK_SCATTER
        __syncthreads();

        if (tid < NP) {
            const int g  = tid;
            int c = 0;
#pragma unroll
            for (int j = 0; j < 32; ++j) c += __popc(s_mask[g * 32 + j]);
            const int st = g ? (s_scan[g - 1] & 0xffff) : 0;
            const int qs = g ? (s_scan[g - 1] >> 16) : 0;
            const int nq = (c + RB - 1) >> 2;
            for (int k = 0; k < nq; ++k) {
                int* rec = ws + 16 + (size_t)(qs + k) * RECS;
#pragma unroll
                for (int r = 0; r < RB; ++r) {
                    const int idx = k * RB + r;
                    rec[r] = (idx < c) ? s_sorted[st + idx] : -1;
                }
                rec[RB] = g;
            }
        }
        if (tid == 0) s_nq = s_scan[NP - 1] >> 16;
        __syncthreads();   // record stores drained before fence/publish
        if (tid == 0) {
            __threadfence();   // agent scope: push records toward L3
            __hip_atomic_store((unsigned*)ws, (TAGHI << 16) | (unsigned)s_nq,
                               __ATOMIC_RELEASE, __HIP_MEMORY_SCOPE_AGENT);
        }
        __syncthreads();
    } else {
        if (tid == 0) {
            unsigned v;
            do {
                v = __hip_atomic_load((const unsigned*)ws, __ATOMIC_ACQUIRE,
                                      __HIP_MEMORY_SCOPE_AGENT);
            } while ((v >> 16) != TAGHI);
            s_nq = (int)(v & 0xffffu);
        }
        __syncthreads();
    }
    const int nquads = s_nq;

    // ---------------- phase 2: R15 gemv body (byte-for-byte) ----------------
    constexpr int q8 = NB / 8;
    const int Lg = (b & 7) * q8 + (b >> 3);
    const int quad = Lg >> 1;
    const int op   = Lg & 1;

    if (quad >= nquads) return;
    const int* rec = ws + 16 + (size_t)quad * RECS;
    const int id = rec[RB];

    const int msg_to = *msg_to_p;
    const int order  = *order_p;
    const int sub = tid >> 6;        // 0..7: h-phase (one wave each)
    const int l   = tid & 63;        // col-quad within 256-col panel
    const int o0  = op * OC;

#pragma unroll
    for (int r = 0; r < RB; ++r) {
        const int row = rec[r];
        float p = 0.0f;
        if (row >= 0) {
            p = 1.0f;
            for (int i = 0; i < order; ++i)
                if (i != msg_to)
                    p *= inp[((size_t)i * N + row) * H_ + tid];
        }
        fp_s[tid][r] = p;
    }
    __syncthreads();

    const float* __restrict__ wbase =
        params + (size_t)id * H_ * O_ + (size_t)sub * O_ + o0 + 4 * l;

    float4 a0 = make_float4(0,0,0,0), a1 = a0, a2 = a0, a3 = a0;

#define FMA4(acc, s, wv) acc.x += (s) * wv.x; acc.y += (s) * wv.y;    \
                         acc.z += (s) * wv.z; acc.w += (s) * wv.w;
#pragma unroll 8
    for (int hh = 0; hh < H_ / HPH; ++hh) {
        const float4 w = *(const float4*)(wbase + (size_t)hh * HPH * O_);
        const float4 f = *(const float4*)&fp_s[HPH * hh + sub][0];
        FMA4(a0, f.x, w)
        FMA4(a1, f.y, w)
        FMA4(a2, f.z, w)
        FMA4(a3, f.w, w)
    }
#undef FMA4

    __syncthreads();   // block 0's build reads of red region long done
    red[sub][0][l] = a0;
    red[sub][1][l] = a1;
    red[sub][2][l] = a2;
    red[sub][3][l] = a3;
    __syncthreads();

    if (tid < RB * 64) {
        const int r  = tid >> 6;
        const int l2 = tid & 63;
        const int row = rec[r];
        if (row >= 0) {
            float4 s = red[0][r][l2];
#pragma unroll
            for (int ss = 1; ss < HPH; ++ss) {
                const float4 p = red[ss][r][l2];
                s.x += p.x; s.y += p.y; s.z += p.z; s.w += p.w;
            }
            const float4 bv = *(const float4*)(bias + (size_t)id * O_ + o0 + 4 * l2);
            s.x += bv.x; s.y += bv.y; s.z += bv.z; s.w += bv.w;
            *(float4*)(out + (size_t)row * O_ + o0 + 4 * l2) = s;
        }
    }
}

// ---------------------------------------------------------------------- launch
extern "C" void kernel_launch(void* const* d_in, const int* in_sizes, int n_in,
                              void* d_out, int out_size, void* d_ws, size_t ws_size,
                              hipStream_t stream) {
    const int*   x      = (const int*)d_in[0];
    const int*   fact   = (const int*)d_in[1];
    const float* inp    = (const float*)d_in[2];
    const float* params = (const float*)d_in[3];
    const float* bias   = (const float*)d_in[4];
    const int*   msg_to = (const int*)d_in[5];
    const int*   order  = (const int*)d_in[6];
    float*       out    = (float*)d_out;

    const int N = in_sizes[1] / 2;   // 1024
    int* ws = (int*)d_ws;

    hipLaunchKernelGGL(fused_gemv, dim3(NB), dim3(512), 0, stream,
                       x, fact, inp, params, bias, msg_to, order, out, ws, N);
}

// Round 21
// 43.330 us; speedup vs baseline: 1.0508x; 1.0508x over previous
//
#include <hip/hip_runtime.h>

#define NATOMS 13
#define NP (NATOMS * NATOMS)   // 169

constexpr int N_ = 1024;   // rows
constexpr int H_ = 512;    // inner dim
constexpr int O_ = 512;    // output dim
constexpr int RB = 4;      // rows per W stream (quad)
constexpr int OSPLIT = 2;
constexpr int OC = O_ / OSPLIT;        // 256 cols per panel (1KB contiguous)
constexpr int HPH = 8;                 // h-phases = waves per block
constexpr int MAXQUAD = 384;           // >= sum ceil(c_g/4) (<=382)
constexpr int NB = MAXQUAD * OSPLIT;   // 768 blocks (div by 8)
constexpr int RECS = 8;    // ints per quad record: rows[4], id, pad

// ws ints: [0] nquads; records at ws+16: [quad*RECS + {0..3}] rows, [+4] id
// ----------------------------------------------------------------- build quads
// Latency-optimized: 1024 threads (1/row), single-pass histogram + scatter,
// 8-step packed Hillis-Steele scan (lo16: row starts, hi16: quad starts).
__global__ __launch_bounds__(1024)
void build_quads(const int* __restrict__ x,
                 const int* __restrict__ fact,
                 int* __restrict__ ws, int N) {
    __shared__ int s_id[N_];
    __shared__ int s_cnt[NP];
    __shared__ int s_pos[NP];
    __shared__ int s_scan[256];
    __shared__ int s_sorted[N_];
    const int tid = threadIdx.x;

    if (tid < NP) { s_cnt[tid] = 0; s_pos[tid] = 0; }
    __syncthreads();

    // one thread per row: id + histogram (single pass)
    const int f0 = fact[2 * tid];
    const int id = x[f0 * 3 + 1] * NATOMS + x[f0 * 3 + 2];
    s_id[tid] = id;
    atomicAdd(&s_cnt[id], 1);
    __syncthreads();

    // packed inclusive scan over 256 slots (zero beyond NP)
    if (tid < 256) {
        const int c = (tid < NP) ? s_cnt[tid] : 0;
        s_scan[tid] = c | (((c + RB - 1) >> 2) << 16);
    }
    __syncthreads();
#pragma unroll
    for (int off = 1; off < 256; off <<= 1) {
        int nv = 0;
        if (tid < 256) {
            nv = s_scan[tid];
            if (tid >= off) nv += s_scan[tid - off];
        }
        __syncthreads();
        if (tid < 256) s_scan[tid] = nv;
        __syncthreads();
    }
    if (tid == 0) ws[0] = s_scan[NP - 1] >> 16;   // nquads

    // scatter rows into group-sorted order (single pass)
    const int st_me = id ? (s_scan[id - 1] & 0xffff) : 0;
    const int p = atomicAdd(&s_pos[id], 1);
    s_sorted[st_me + p] = tid;
    __syncthreads();

    // emit quad records: one group per thread
    if (tid < NP) {
        const int g  = tid;
        const int c  = s_cnt[g];
        const int st = g ? (s_scan[g - 1] & 0xffff) : 0;
        const int qs = g ? (s_scan[g - 1] >> 16) : 0;
        const int nq = (c + RB - 1) >> 2;
        for (int k = 0; k < nq; ++k) {
            int* rec = ws + 16 + (size_t)(qs + k) * RECS;
#pragma unroll
            for (int r = 0; r < RB; ++r) {
                const int idx = k * RB + r;
                rec[r] = (idx < c) ? s_sorted[st + idx] : -1;
            }
            rec[RB] = g;
        }
    }
}

// ------------------------------------------------------------------ quad GEMV
// One block per (quad, o-panel), 512 threads = 8 waves streaming disjoint
// h-rows of the same 512x256 W panel as 1KB-contiguous wave loads.
// 8-way LDS reduce, bias, direct float4 stores. No atomics, no memset.
__global__ __launch_bounds__(512)
void quad_gemv(const int* __restrict__ ws,
               const float* __restrict__ inp,
               const float* __restrict__ params,
               const float* __restrict__ bias,
               const int* __restrict__ msg_to_p,
               const int* __restrict__ order_p,
               float* __restrict__ out, int N) {
    constexpr int q8 = NB / 8;
    const int b = blockIdx.x;
    const int Lg = (b & 7) * q8 + (b >> 3);
    const int quad = Lg >> 1;
    const int op   = Lg & 1;

    if (quad >= ws[0]) return;
    const int* rec = ws + 16 + (size_t)quad * RECS;
    const int id = rec[RB];

    const int msg_to = *msg_to_p;
    const int order  = *order_p;
    const int tid = threadIdx.x;
    const int sub = tid >> 6;        // 0..7: h-phase (one wave each)
    const int l   = tid & 63;        // col-quad within 256-col panel
    const int o0  = op * OC;

    __shared__ float  fp_s[H_][RB];        // 8 KB, [h][r]
    __shared__ float4 red[HPH][RB][64];    // 32 KB, [sub][r][l]

#pragma unroll
    for (int r = 0; r < RB; ++r) {
        const int row = rec[r];
        float p = 0.0f;
        if (row >= 0) {
            p = 1.0f;
            for (int i = 0; i < order; ++i)
                if (i != msg_to)
                    p *= inp[((size_t)i * N + row) * H_ + tid];
        }
        fp_s[tid][r] = p;
    }
    __syncthreads();

    const float* __restrict__ wbase =
        params + (size_t)id * H_ * O_ + (size_t)sub * O_ + o0 + 4 * l;

    float4 a0 = make_float4(0,0,0,0), a1 = a0, a2 = a0, a3 = a0;

#define FMA4(acc, s, wv) acc.x += (s) * wv.x; acc.y += (s) * wv.y;    \
                         acc.z += (s) * wv.z; acc.w += (s) * wv.w;
#pragma unroll 8
    for (int hh = 0; hh < H_ / HPH; ++hh) {
        const float4 w = *(const float4*)(wbase + (size_t)hh * HPH * O_);
        const float4 f = *(const float4*)&fp_s[HPH * hh + sub][0];
        FMA4(a0, f.x, w)
        FMA4(a1, f.y, w)
        FMA4(a2, f.z, w)
        FMA4(a3, f.w, w)
    }
#undef FMA4

    red[sub][0][l] = a0;
    red[sub][1][l] = a1;
    red[sub][2][l] = a2;
    red[sub][3][l] = a3;
    __syncthreads();

    if (tid < RB * 64) {
        const int r  = tid >> 6;
        const int l2 = tid & 63;
        const int row = rec[r];
        if (row >= 0) {
            float4 s = red[0][r][l2];
#pragma unroll
            for (int ss = 1; ss < HPH; ++ss) {
                const float4 p = red[ss][r][l2];
                s.x += p.x; s.y += p.y; s.z += p.z; s.w += p.w;
            }
            const float4 bv = *(const float4*)(bias + (size_t)id * O_ + o0 + 4 * l2);
            s.x += bv.x; s.y += bv.y; s.z += bv.z; s.w += bv.w;
            *(float4*)(out + (size_t)row * O_ + o0 + 4 * l2) = s;
        }
    }
}

// ---------------------------------------------------------------------- launch
extern "C" void kernel_launch(void* const* d_in, const int* in_sizes, int n_in,
                              void* d_out, int out_size, void* d_ws, size_t ws_size,
                              hipStream_t stream) {
    const int*   x      = (const int*)d_in[0];
    const int*   fact   = (const int*)d_in[1];
    const float* inp    = (const float*)d_in[2];
    const float* params = (const float*)d_in[3];
    const float* bias   = (const float*)d_in[4];
    const int*   msg_to = (const int*)d_in[5];
    const int*   order  = (const int*)d_in[6];
    float*       out    = (float*)d_out;

    const int N = in_sizes[1] / 2;   // 1024
    int* ws = (int*)d_ws;

    hipLaunchKernelGGL(build_quads, dim3(1), dim3(1024), 0, stream,
                       x, fact, ws, N);

    hipLaunchKernelGGL(quad_gemv, dim3(NB), dim3(512), 0, stream,
                       ws, inp, params, bias, msg_to, order, out, N);
}